// Round 7
// baseline (167.986 us; speedup 1.0000x reference)
//
#include <hip/hip_runtime.h>
#include <hip/hip_bf16.h>
#include <math.h>

#define LEN_IN   16660
#define D_MODEL  256
#define N_HEADS  8
#define HEAD_DIM 32
#define N_LEVELS 4
#define N_POINTS 4

typedef __attribute__((ext_vector_type(8))) short short8v;
typedef __attribute__((ext_vector_type(4))) float f32x4;
typedef _Float16 f16x2 __attribute__((ext_vector_type(2)));

__device__ __forceinline__ unsigned short f2bf(float f) {
  unsigned u = __float_as_uint(f);
  unsigned r = (u + 0x7fffu + ((u >> 16) & 1u)) >> 16;
  return (unsigned short)r;
}
__device__ __forceinline__ float bf2f(unsigned short h) {
  return __uint_as_float(((unsigned)h) << 16);
}
__device__ __forceinline__ unsigned f2h16(float f) {  // f32 -> f16 bits (RN)
  _Float16 h = (_Float16)f;
  union { unsigned short u; _Float16 h; } c;
  c.h = h;
  return (unsigned)c.u;
}
__device__ __forceinline__ f16x2 u2h(unsigned u) {
  union { unsigned u; f16x2 h; } c;
  c.u = u;
  return c.h;
}

// ---------------------------------------------------------------------------
// f32 tiled GEMM — used once for Wqo = W_q @ W_off (256x256x256).
// ---------------------------------------------------------------------------
__global__ __launch_bounds__(256) void gemm_f32(
    const float* __restrict__ A, const float* __restrict__ B,
    const float* __restrict__ bias, float* __restrict__ C,
    int M, int N, int K) {
  const int BM = 64, BN = 64, BK = 16;
  __shared__ float As[BK][BM + 1];
  __shared__ float Bs[BK][BN];
  int tid = threadIdx.x;
  int brow = blockIdx.x * BM;
  int bcol = blockIdx.y * BN;
  int tx = tid & 15, ty = tid >> 4;
  float acc[4][4] = {};
  for (int k0 = 0; k0 < K; k0 += BK) {
    #pragma unroll
    for (int i = 0; i < 4; i++) {
      int idx = tid + i * 256;
      int r = idx >> 4, c = idx & 15;
      float v = 0.f;
      int row = brow + r;
      if (row < M) v = A[(size_t)row * K + k0 + c];
      As[c][r] = v;
    }
    #pragma unroll
    for (int i = 0; i < 4; i++) {
      int idx = tid + i * 256;
      int r = idx >> 6, c = idx & 63;
      Bs[r][c] = B[(size_t)(k0 + r) * N + bcol + c];
    }
    __syncthreads();
    #pragma unroll
    for (int kk = 0; kk < BK; kk++) {
      float a[4], b[4];
      #pragma unroll
      for (int i = 0; i < 4; i++) a[i] = As[kk][ty * 4 + i];
      #pragma unroll
      for (int j = 0; j < 4; j++) b[j] = Bs[kk][tx * 4 + j];
      #pragma unroll
      for (int i = 0; i < 4; i++)
        #pragma unroll
        for (int j = 0; j < 4; j++) acc[i][j] += a[i] * b[j];
    }
    __syncthreads();
  }
  #pragma unroll
  for (int i = 0; i < 4; i++) {
    int r = brow + ty * 4 + i;
    if (r >= M) continue;
    #pragma unroll
    for (int j = 0; j < 4; j++) {
      int c = bcol + tx * 4 + j;
      float b = bias ? bias[c] : 0.f;
      C[(size_t)r * N + c] = acc[i][j] + b;
    }
  }
}

// bqo[j] = sum_i bq[i] * Woff[i][j] + boff[j]
__global__ void bqo_kernel(const float* __restrict__ bq,
                           const float* __restrict__ Woff,
                           const float* __restrict__ boff,
                           float* __restrict__ bqo) {
  int j = threadIdx.x;
  float s = boff[j];
  for (int i = 0; i < 256; i++) s += bq[i] * Woff[(size_t)i * 256 + j];
  bqo[j] = s;
}

// ---------------------------------------------------------------------------
// Prep: transpose + bf16-cast 5 weight matrices. Bt[n][k] = W[k][n].
// W_q, Wqo, W_o get hi+lo (residual) pairs for split-precision MFMA.
// ---------------------------------------------------------------------------
__global__ __launch_bounds__(256) void prep_B(
    const float* __restrict__ Wk, const float* __restrict__ Wv,
    const float* __restrict__ Wq, const float* __restrict__ Wqo,
    const float* __restrict__ Wo,
    unsigned short* __restrict__ Btk, unsigned short* __restrict__ Btv,
    unsigned short* __restrict__ Btqh, unsigned short* __restrict__ Btql,
    unsigned short* __restrict__ Btoffh, unsigned short* __restrict__ Btoffl,
    unsigned short* __restrict__ Btoh, unsigned short* __restrict__ Btol) {
  __shared__ float tile[64][65];
  int b = blockIdx.x;
  int mat = b >> 4, t = b & 15;
  int ti = t >> 2, tj = t & 3;  // ti: k-tile, tj: n-tile
  const float* W = (mat == 0) ? Wk : (mat == 1) ? Wv : (mat == 2) ? Wq
                 : (mat == 3) ? Wqo : Wo;
  int tid = threadIdx.x;
  #pragma unroll
  for (int i = 0; i < 16; i++) {
    int idx = tid + i * 256;
    int kr = idx >> 6, nc = idx & 63;
    tile[kr][nc] = W[(size_t)(ti * 64 + kr) * 256 + tj * 64 + nc];
  }
  __syncthreads();
  #pragma unroll
  for (int i = 0; i < 16; i++) {
    int idx = tid + i * 256;
    int nr = idx >> 6, kc = idx & 63;
    float v = tile[kc][nr];
    unsigned short h = f2bf(v);
    size_t o = (size_t)(tj * 64 + nr) * 256 + ti * 64 + kc;
    if (mat == 0) Btk[o] = h;
    else if (mat == 1) Btv[o] = h;
    else {
      unsigned short* Bh = (mat == 2) ? Btqh : (mat == 3) ? Btoffh : Btoh;
      unsigned short* Bl = (mat == 2) ? Btql : (mat == 3) ? Btoffl : Btol;
      Bh[o] = h;
      Bl[o] = f2bf(v - bf2f(h));
    }
  }
}

// ---------------------------------------------------------------------------
// Fused q-proj + off-proj: both read the same A (query) tile.
// qp = query@Wq + bq ; offs = query@Wqo + bqo. hi/lo split (~f32 accuracy).
// ---------------------------------------------------------------------------
__global__ __launch_bounds__(256) void gemm_qoff_mfma(
    const float* __restrict__ A,
    const unsigned short* __restrict__ Bqh, const unsigned short* __restrict__ Bql,
    const unsigned short* __restrict__ Boh, const unsigned short* __restrict__ Bol,
    const float* __restrict__ biasq, const float* __restrict__ biaso,
    float* __restrict__ Cq, float* __restrict__ Co, int M) {
  const int P = 40;
  __shared__ short Ah[64 * P], Al[64 * P];
  __shared__ short Bqhs[64 * P], Bqls[64 * P], Bohs[64 * P], Bols[64 * P];
  int tid = threadIdx.x;
  int m0 = blockIdx.x * 64, n0 = blockIdx.y * 64;
  int w = tid >> 6, l = tid & 63;
  int r = l & 15, g = l >> 4;
  int mi = (w >> 1) * 32, ni = (w & 1) * 32;
  int sm = tid >> 2, sp = tid & 3;

  f32x4 accq[2][2], acco[2][2];
  #pragma unroll
  for (int a = 0; a < 2; a++)
    #pragma unroll
    for (int b = 0; b < 2; b++) {
      accq[a][b] = (f32x4){0.f, 0.f, 0.f, 0.f};
      acco[a][b] = (f32x4){0.f, 0.f, 0.f, 0.f};
    }

  for (int k0 = 0; k0 < 256; k0 += 32) {
    int gm = m0 + sm;
    float f[8];
    if (gm < M) {
      const float* src = A + (size_t)gm * 256 + k0 + sp * 8;
      float4 u0 = *(const float4*)src;
      float4 u1 = *(const float4*)(src + 4);
      f[0] = u0.x; f[1] = u0.y; f[2] = u0.z; f[3] = u0.w;
      f[4] = u1.x; f[5] = u1.y; f[6] = u1.z; f[7] = u1.w;
    } else {
      #pragma unroll
      for (int j = 0; j < 8; j++) f[j] = 0.f;
    }
    short8v hv, lv;
    #pragma unroll
    for (int j = 0; j < 8; j++) {
      unsigned short h = f2bf(f[j]);
      hv[j] = (short)h;
      lv[j] = (short)f2bf(f[j] - bf2f(h));
    }
    *(short8v*)&Ah[sm * P + sp * 8] = hv;
    *(short8v*)&Al[sm * P + sp * 8] = lv;
    *(short8v*)&Bqhs[sm * P + sp * 8] =
        *(const short8v*)&Bqh[(size_t)(n0 + sm) * 256 + k0 + sp * 8];
    *(short8v*)&Bqls[sm * P + sp * 8] =
        *(const short8v*)&Bql[(size_t)(n0 + sm) * 256 + k0 + sp * 8];
    *(short8v*)&Bohs[sm * P + sp * 8] =
        *(const short8v*)&Boh[(size_t)(n0 + sm) * 256 + k0 + sp * 8];
    *(short8v*)&Bols[sm * P + sp * 8] =
        *(const short8v*)&Bol[(size_t)(n0 + sm) * 256 + k0 + sp * 8];
    __syncthreads();

    short8v ah[2], al[2], qh[2], ql[2], oh[2], ol[2];
    #pragma unroll
    for (int a = 0; a < 2; a++) {
      ah[a] = *(short8v*)&Ah[(mi + a * 16 + r) * P + g * 8];
      al[a] = *(short8v*)&Al[(mi + a * 16 + r) * P + g * 8];
    }
    #pragma unroll
    for (int b = 0; b < 2; b++) {
      qh[b] = *(short8v*)&Bqhs[(ni + b * 16 + r) * P + g * 8];
      ql[b] = *(short8v*)&Bqls[(ni + b * 16 + r) * P + g * 8];
      oh[b] = *(short8v*)&Bohs[(ni + b * 16 + r) * P + g * 8];
      ol[b] = *(short8v*)&Bols[(ni + b * 16 + r) * P + g * 8];
    }
    #pragma unroll
    for (int a = 0; a < 2; a++)
      #pragma unroll
      for (int b = 0; b < 2; b++) {
        accq[a][b] = __builtin_amdgcn_mfma_f32_16x16x32_bf16(ah[a], qh[b], accq[a][b], 0, 0, 0);
        accq[a][b] = __builtin_amdgcn_mfma_f32_16x16x32_bf16(al[a], qh[b], accq[a][b], 0, 0, 0);
        accq[a][b] = __builtin_amdgcn_mfma_f32_16x16x32_bf16(ah[a], ql[b], accq[a][b], 0, 0, 0);
        acco[a][b] = __builtin_amdgcn_mfma_f32_16x16x32_bf16(ah[a], oh[b], acco[a][b], 0, 0, 0);
        acco[a][b] = __builtin_amdgcn_mfma_f32_16x16x32_bf16(al[a], oh[b], acco[a][b], 0, 0, 0);
        acco[a][b] = __builtin_amdgcn_mfma_f32_16x16x32_bf16(ah[a], ol[b], acco[a][b], 0, 0, 0);
      }
    __syncthreads();
  }

  #pragma unroll
  for (int a = 0; a < 2; a++)
    #pragma unroll
    for (int b = 0; b < 2; b++) {
      int col = n0 + ni + b * 16 + r;
      float bq = biasq[col], bo = biaso[col];
      #pragma unroll
      for (int i = 0; i < 4; i++) {
        int row = m0 + mi + a * 16 + g * 4 + i;
        if (row < M) {
          Cq[(size_t)row * 256 + col] = accq[a][b][i] + bq;
          Co[(size_t)row * 256 + col] = acco[a][b][i] + bo;
        }
      }
    }
}

// ---------------------------------------------------------------------------
// hi/lo-split bf16 MFMA GEMM (~f32 accuracy), f32 out. For output projection.
// ---------------------------------------------------------------------------
__global__ __launch_bounds__(256) void gemm_hl_mfma(
    const float* __restrict__ A,
    const unsigned short* __restrict__ Bth,
    const unsigned short* __restrict__ Btl,
    const float* __restrict__ bias, float* __restrict__ C, int M) {
  const int P = 40;
  __shared__ short Ah[64 * P], Al[64 * P], Bh[64 * P], Bl[64 * P];
  int tid = threadIdx.x;
  int m0 = blockIdx.x * 64, n0 = blockIdx.y * 64;
  int w = tid >> 6, l = tid & 63;
  int r = l & 15, g = l >> 4;
  int mi = (w >> 1) * 32, ni = (w & 1) * 32;
  int sm = tid >> 2, sp = tid & 3;

  f32x4 acc[2][2];
  #pragma unroll
  for (int a = 0; a < 2; a++)
    #pragma unroll
    for (int b = 0; b < 2; b++) acc[a][b] = (f32x4){0.f, 0.f, 0.f, 0.f};

  for (int k0 = 0; k0 < 256; k0 += 32) {
    int gm = m0 + sm;
    float f[8];
    if (gm < M) {
      const float* src = A + (size_t)gm * 256 + k0 + sp * 8;
      float4 u0 = *(const float4*)src;
      float4 u1 = *(const float4*)(src + 4);
      f[0] = u0.x; f[1] = u0.y; f[2] = u0.z; f[3] = u0.w;
      f[4] = u1.x; f[5] = u1.y; f[6] = u1.z; f[7] = u1.w;
    } else {
      #pragma unroll
      for (int j = 0; j < 8; j++) f[j] = 0.f;
    }
    short8v hv, lv;
    #pragma unroll
    for (int j = 0; j < 8; j++) {
      unsigned short h = f2bf(f[j]);
      hv[j] = (short)h;
      lv[j] = (short)f2bf(f[j] - bf2f(h));
    }
    *(short8v*)&Ah[sm * P + sp * 8] = hv;
    *(short8v*)&Al[sm * P + sp * 8] = lv;
    *(short8v*)&Bh[sm * P + sp * 8] =
        *(const short8v*)&Bth[(size_t)(n0 + sm) * 256 + k0 + sp * 8];
    *(short8v*)&Bl[sm * P + sp * 8] =
        *(const short8v*)&Btl[(size_t)(n0 + sm) * 256 + k0 + sp * 8];
    __syncthreads();

    short8v ah[2], al[2], bh[2], bl[2];
    #pragma unroll
    for (int a = 0; a < 2; a++) {
      ah[a] = *(short8v*)&Ah[(mi + a * 16 + r) * P + g * 8];
      al[a] = *(short8v*)&Al[(mi + a * 16 + r) * P + g * 8];
    }
    #pragma unroll
    for (int b = 0; b < 2; b++) {
      bh[b] = *(short8v*)&Bh[(ni + b * 16 + r) * P + g * 8];
      bl[b] = *(short8v*)&Bl[(ni + b * 16 + r) * P + g * 8];
    }
    #pragma unroll
    for (int a = 0; a < 2; a++)
      #pragma unroll
      for (int b = 0; b < 2; b++) {
        acc[a][b] = __builtin_amdgcn_mfma_f32_16x16x32_bf16(ah[a], bh[b], acc[a][b], 0, 0, 0);
        acc[a][b] = __builtin_amdgcn_mfma_f32_16x16x32_bf16(al[a], bh[b], acc[a][b], 0, 0, 0);
        acc[a][b] = __builtin_amdgcn_mfma_f32_16x16x32_bf16(ah[a], bl[b], acc[a][b], 0, 0, 0);
      }
    __syncthreads();
  }

  #pragma unroll
  for (int a = 0; a < 2; a++)
    #pragma unroll
    for (int b = 0; b < 2; b++) {
      int col = n0 + ni + b * 16 + r;
      float bc = bias[col];
      #pragma unroll
      for (int i = 0; i < 4; i++) {
        int row = m0 + mi + a * 16 + g * 4 + i;
        if (row < M) C[(size_t)row * 256 + col] = acc[a][b][i] + bc;
      }
    }
}

// ---------------------------------------------------------------------------
// Fused K+V projection, bf16 MFMA, hi/lo on A; packed **f16** {k|v<<16} out.
// ---------------------------------------------------------------------------
__global__ __launch_bounds__(256) void gemm_kv_mfma(
    const float* __restrict__ A,
    const unsigned short* __restrict__ Btk,
    const unsigned short* __restrict__ Btv,
    const float* __restrict__ bk, const float* __restrict__ bv,
    unsigned* __restrict__ kvout, int M) {
  const int P = 40;
  __shared__ short Ah[64 * P], Al[64 * P], Bk[64 * P], Bv[64 * P];
  int tid = threadIdx.x;
  int m0 = blockIdx.x * 64, n0 = blockIdx.y * 64;
  int w = tid >> 6, l = tid & 63;
  int r = l & 15, g = l >> 4;
  int mi = (w >> 1) * 32, ni = (w & 1) * 32;
  int sm = tid >> 2, sp = tid & 3;

  f32x4 acck[2][2], accv[2][2];
  #pragma unroll
  for (int a = 0; a < 2; a++)
    #pragma unroll
    for (int b = 0; b < 2; b++) {
      acck[a][b] = (f32x4){0.f, 0.f, 0.f, 0.f};
      accv[a][b] = (f32x4){0.f, 0.f, 0.f, 0.f};
    }

  for (int k0 = 0; k0 < 256; k0 += 32) {
    int gm = m0 + sm;
    float f[8];
    if (gm < M) {
      const float* src = A + (size_t)gm * 256 + k0 + sp * 8;
      float4 u0 = *(const float4*)src;
      float4 u1 = *(const float4*)(src + 4);
      f[0] = u0.x; f[1] = u0.y; f[2] = u0.z; f[3] = u0.w;
      f[4] = u1.x; f[5] = u1.y; f[6] = u1.z; f[7] = u1.w;
    } else {
      #pragma unroll
      for (int j = 0; j < 8; j++) f[j] = 0.f;
    }
    short8v hv, lv;
    #pragma unroll
    for (int j = 0; j < 8; j++) {
      unsigned short h = f2bf(f[j]);
      hv[j] = (short)h;
      lv[j] = (short)f2bf(f[j] - bf2f(h));
    }
    *(short8v*)&Ah[sm * P + sp * 8] = hv;
    *(short8v*)&Al[sm * P + sp * 8] = lv;
    *(short8v*)&Bk[sm * P + sp * 8] =
        *(const short8v*)&Btk[(size_t)(n0 + sm) * 256 + k0 + sp * 8];
    *(short8v*)&Bv[sm * P + sp * 8] =
        *(const short8v*)&Btv[(size_t)(n0 + sm) * 256 + k0 + sp * 8];
    __syncthreads();

    short8v ah[2], al[2], fbk[2], fbv[2];
    #pragma unroll
    for (int a = 0; a < 2; a++) {
      ah[a] = *(short8v*)&Ah[(mi + a * 16 + r) * P + g * 8];
      al[a] = *(short8v*)&Al[(mi + a * 16 + r) * P + g * 8];
    }
    #pragma unroll
    for (int b = 0; b < 2; b++) {
      fbk[b] = *(short8v*)&Bk[(ni + b * 16 + r) * P + g * 8];
      fbv[b] = *(short8v*)&Bv[(ni + b * 16 + r) * P + g * 8];
    }
    #pragma unroll
    for (int a = 0; a < 2; a++)
      #pragma unroll
      for (int b = 0; b < 2; b++) {
        acck[a][b] = __builtin_amdgcn_mfma_f32_16x16x32_bf16(ah[a], fbk[b], acck[a][b], 0, 0, 0);
        acck[a][b] = __builtin_amdgcn_mfma_f32_16x16x32_bf16(al[a], fbk[b], acck[a][b], 0, 0, 0);
        accv[a][b] = __builtin_amdgcn_mfma_f32_16x16x32_bf16(ah[a], fbv[b], accv[a][b], 0, 0, 0);
        accv[a][b] = __builtin_amdgcn_mfma_f32_16x16x32_bf16(al[a], fbv[b], accv[a][b], 0, 0, 0);
      }
    __syncthreads();
  }

  #pragma unroll
  for (int a = 0; a < 2; a++)
    #pragma unroll
    for (int b = 0; b < 2; b++) {
      int col = n0 + ni + b * 16 + r;
      float bkc = bk[col], bvc = bv[col];
      #pragma unroll
      for (int i = 0; i < 4; i++) {
        int row = m0 + mi + a * 16 + g * 4 + i;
        if (row < M) {
          unsigned kh = f2h16(acck[a][b][i] + bkc);
          unsigned vh = f2h16(accv[a][b][i] + bvc);
          kvout[(size_t)row * 256 + col] = kh | (vh << 16);
        }
      }
    }
}

// ---------------------------------------------------------------------------
// Sampling + attention v3: one wave per (query, head).
// Lane = (point lane>>2, 8-channel chunk (lane&3)*8). Single 16-point pass.
// Taps weighted with packed f16 FMA on the {k,v} pair — no unpacking.
// ---------------------------------------------------------------------------
__global__ __launch_bounds__(256) void sample_attn(
    const float* __restrict__ qp,
    const float* __restrict__ offs,
    const float* __restrict__ rp,
    const unsigned* __restrict__ kv,   // packed f16 {k | v<<16}
    float* __restrict__ attn_out) {
  __shared__ float lbuf[4][16];
  __shared__ float ebuf[4][16];
  __shared__ float vbuf[4][16][36];   // +4 pad: 16-way -> 2-way bank alias

  int tid = threadIdx.x;
  int wslot = tid >> 6;
  int lane = tid & 63;
  int wid = blockIdx.x * 4 + wslot;
  int q = wid >> 3;
  int h = wid & 7;

  int pt = lane >> 2;        // point 0..15
  int c8 = (lane & 3) * 8;   // channel chunk base
  int l5 = lane & 31;

  float offv = offs[(size_t)q * D_MODEL + h * 32 + l5];
  float rpv = (l5 < 8) ? rp[(size_t)q * 8 + l5] : 0.f;

  int l = pt >> 2, pp = pt & 3;
  int W = 112 >> l;
  int start = (int)((50176u - (50176u >> (2 * l))) / 3u);  // 0,12544,15680,16464

  float off_x = __shfl(offv, l * 8 + pp * 2 + 0, 64);
  float off_y = __shfl(offv, l * 8 + pp * 2 + 1, 64);
  float rp_x = __shfl(rpv, l * 2 + 0, 64);
  float rp_y = __shfl(rpv, l * 2 + 1, 64);

  float x = rp_x * (float)W + off_x - 0.5f;
  float y = rp_y * (float)W + off_y - 0.5f;
  float x0f = floorf(x), y0f = floorf(y);
  float lx = x - x0f, ly = y - y0f;
  int x0 = (int)x0f, y0 = (int)y0f;
  float wx0 = 1.f - lx, wy0 = 1.f - ly;
  float tw[4] = {wy0 * wx0, wy0 * lx, ly * wx0, ly * lx};

  const unsigned* base = kv + (size_t)0;
  int hoff = h * 32 + c8;

  f16x2 acc[8];
  #pragma unroll
  for (int j = 0; j < 8; j++) acc[j] = (f16x2){(_Float16)0.f, (_Float16)0.f};

  #pragma unroll
  for (int tap = 0; tap < 4; tap++) {
    int yy = y0 + (tap >> 1), xx = x0 + (tap & 1);
    bool valid = ((unsigned)xx < (unsigned)W) & ((unsigned)yy < (unsigned)W);
    float wgt = valid ? tw[tap] : 0.f;
    int pix = valid ? (start + yy * W + xx) : start;
    const unsigned* p = base + (size_t)pix * D_MODEL + hoff;
    uint4 u0 = *(const uint4*)p;
    uint4 u1 = *(const uint4*)(p + 4);
    _Float16 wh = (_Float16)wgt;
    f16x2 w2 = {wh, wh};
    acc[0] += w2 * u2h(u0.x);
    acc[1] += w2 * u2h(u0.y);
    acc[2] += w2 * u2h(u0.z);
    acc[3] += w2 * u2h(u0.w);
    acc[4] += w2 * u2h(u1.x);
    acc[5] += w2 * u2h(u1.y);
    acc[6] += w2 * u2h(u1.z);
    acc[7] += w2 * u2h(u1.w);
  }

  // q . k over this lane's 8 channels (k = low half of acc pairs)
  const float* qsrc = qp + (size_t)q * D_MODEL + hoff;
  float4 qa = *(const float4*)qsrc;
  float4 qb = *(const float4*)(qsrc + 4);
  float dot = qa.x * (float)acc[0][0] + qa.y * (float)acc[1][0]
            + qa.z * (float)acc[2][0] + qa.w * (float)acc[3][0]
            + qb.x * (float)acc[4][0] + qb.y * (float)acc[5][0]
            + qb.z * (float)acc[6][0] + qb.w * (float)acc[7][0];
  dot += __shfl_xor(dot, 1, 64);
  dot += __shfl_xor(dot, 2, 64);
  if ((lane & 3) == 0) lbuf[wslot][pt] = dot * 0.17677669529663687f;

  // v (high halves) to f32, into LDS
  float4 v0 = {(float)acc[0][1], (float)acc[1][1], (float)acc[2][1], (float)acc[3][1]};
  float4 v1 = {(float)acc[4][1], (float)acc[5][1], (float)acc[6][1], (float)acc[7][1]};
  *(float4*)&vbuf[wslot][pt][c8] = v0;
  *(float4*)&vbuf[wslot][pt][c8 + 4] = v1;
  __syncthreads();

  // softmax over 16 points (redundant per 16-lane group, 1 exp per lane)
  float lg = lbuf[wslot][lane & 15];
  float m = lg;
  m = fmaxf(m, __shfl_xor(m, 1, 64));
  m = fmaxf(m, __shfl_xor(m, 2, 64));
  m = fmaxf(m, __shfl_xor(m, 4, 64));
  m = fmaxf(m, __shfl_xor(m, 8, 64));
  float e = __expf(lg - m);
  float s = e;
  s += __shfl_xor(s, 1, 64);
  s += __shfl_xor(s, 2, 64);
  s += __shfl_xor(s, 4, 64);
  s += __shfl_xor(s, 8, 64);
  if (lane < 16) ebuf[wslot][lane] = e;
  float inv = 1.f / s;
  __syncthreads();

  if (lane < 32) {
    float o = 0.f;
    #pragma unroll
    for (int p = 0; p < 16; p++) o += ebuf[wslot][p] * vbuf[wslot][p][lane];
    attn_out[(size_t)q * D_MODEL + h * 32 + lane] = o * inv;
  }
}

extern "C" void kernel_launch(void* const* d_in, const int* in_sizes, int n_in,
                              void* d_out, int out_size, void* d_ws, size_t ws_size,
                              hipStream_t stream) {
  const float* query = (const float*)d_in[0];
  const float* rp    = (const float*)d_in[1];
  const float* inp   = (const float*)d_in[2];
  const float* W_q   = (const float*)d_in[5];
  const float* b_q   = (const float*)d_in[6];
  const float* W_k   = (const float*)d_in[7];
  const float* b_k   = (const float*)d_in[8];
  const float* W_v   = (const float*)d_in[9];
  const float* b_v   = (const float*)d_in[10];
  const float* W_o   = (const float*)d_in[11];
  const float* b_o   = (const float*)d_in[12];
  const float* W_off = (const float*)d_in[13];
  const float* b_off = (const float*)d_in[14];
  float* out = (float*)d_out;

  const size_t nelem = (size_t)LEN_IN * D_MODEL;  // 4,264,960
  float* qp   = (float*)d_ws;
  float* offs = qp + nelem;
  float* attn = offs + nelem;
  unsigned* kvp = (unsigned*)(attn + nelem);
  float* Wqo = (float*)(kvp + nelem);          // 65536 f32
  float* bqo = Wqo + 256 * 256;                // 256 f32
  unsigned short* Btk    = (unsigned short*)(bqo + 256);
  unsigned short* Btv    = Btk + 256 * 256;
  unsigned short* Btqh   = Btv + 256 * 256;
  unsigned short* Btql   = Btqh + 256 * 256;
  unsigned short* Btoffh = Btql + 256 * 256;
  unsigned short* Btoffl = Btoffh + 256 * 256;
  unsigned short* Btoh   = Btoffl + 256 * 256;
  unsigned short* Btol   = Btoh + 256 * 256;

  dim3 blk(256);
  dim3 ggrid((LEN_IN + 63) / 64, D_MODEL / 64);  // (261, 4)

  // Wqo = W_q @ W_off ; bqo = b_q @ W_off + b_off   (off = query@Wqo + bqo)
  gemm_f32<<<dim3(4, 4), blk, 0, stream>>>(W_q, W_off, nullptr, Wqo, 256, 256, 256);
  bqo_kernel<<<1, blk, 0, stream>>>(b_q, W_off, b_off, bqo);
  prep_B<<<80, blk, 0, stream>>>(W_k, W_v, W_q, Wqo, W_o,
                                 Btk, Btv, Btqh, Btql, Btoffh, Btoffl, Btoh, Btol);

  gemm_qoff_mfma<<<ggrid, blk, 0, stream>>>(query, Btqh, Btql, Btoffh, Btoffl,
                                            b_q, bqo, qp, offs, LEN_IN);
  gemm_kv_mfma<<<ggrid, blk, 0, stream>>>(inp, Btk, Btv, b_k, b_v, kvp, LEN_IN);

  int n_blocks = LEN_IN * N_HEADS / 4;  // 33320
  sample_attn<<<n_blocks, blk, 0, stream>>>(qp, offs, rp, kvp, attn);

  gemm_hl_mfma<<<ggrid, blk, 0, stream>>>(attn, Btoh, Btol, b_o, out, LEN_IN);
}

// Round 8
// 147.569 us; speedup vs baseline: 1.1384x; 1.1384x over previous
//
#include <hip/hip_runtime.h>
#include <hip/hip_bf16.h>
#include <math.h>

#define LEN_IN   16660
#define D_MODEL  256
#define N_HEADS  8
#define HEAD_DIM 32
#define N_LEVELS 4
#define N_POINTS 4

typedef __attribute__((ext_vector_type(8))) short short8v;
typedef __attribute__((ext_vector_type(4))) float f32x4;
typedef _Float16 f16x2 __attribute__((ext_vector_type(2)));

__device__ __forceinline__ unsigned short f2bf(float f) {
  unsigned u = __float_as_uint(f);
  unsigned r = (u + 0x7fffu + ((u >> 16) & 1u)) >> 16;
  return (unsigned short)r;
}
__device__ __forceinline__ float bf2f(unsigned short h) {
  return __uint_as_float(((unsigned)h) << 16);
}
__device__ __forceinline__ unsigned f2h16(float f) {  // f32 -> f16 bits (RN)
  _Float16 h = (_Float16)f;
  union { unsigned short u; _Float16 h; } c;
  c.h = h;
  return (unsigned)c.u;
}
__device__ __forceinline__ f16x2 u2h(unsigned u) {
  union { unsigned u; f16x2 h; } c;
  c.u = u;
  return c.h;
}

// ---------------------------------------------------------------------------
// Prep: transpose + bf16-cast 5 weight matrices. Bt[n][k] = W[k][n].
// W_q, W_off, W_o get hi+lo (residual) pairs for split-precision MFMA.
// ---------------------------------------------------------------------------
__global__ __launch_bounds__(256) void prep_B(
    const float* __restrict__ Wk, const float* __restrict__ Wv,
    const float* __restrict__ Wq, const float* __restrict__ Woff,
    const float* __restrict__ Wo,
    unsigned short* __restrict__ Btk, unsigned short* __restrict__ Btv,
    unsigned short* __restrict__ Btqh, unsigned short* __restrict__ Btql,
    unsigned short* __restrict__ Btoffh, unsigned short* __restrict__ Btoffl,
    unsigned short* __restrict__ Btoh, unsigned short* __restrict__ Btol) {
  __shared__ float tile[64][65];
  int b = blockIdx.x;
  int mat = b >> 4, t = b & 15;
  int ti = t >> 2, tj = t & 3;  // ti: k-tile, tj: n-tile
  const float* W = (mat == 0) ? Wk : (mat == 1) ? Wv : (mat == 2) ? Wq
                 : (mat == 3) ? Woff : Wo;
  int tid = threadIdx.x;
  #pragma unroll
  for (int i = 0; i < 16; i++) {
    int idx = tid + i * 256;
    int kr = idx >> 6, nc = idx & 63;
    tile[kr][nc] = W[(size_t)(ti * 64 + kr) * 256 + tj * 64 + nc];
  }
  __syncthreads();
  #pragma unroll
  for (int i = 0; i < 16; i++) {
    int idx = tid + i * 256;
    int nr = idx >> 6, kc = idx & 63;
    float v = tile[kc][nr];
    unsigned short h = f2bf(v);
    size_t o = (size_t)(tj * 64 + nr) * 256 + ti * 64 + kc;
    if (mat == 0) Btk[o] = h;
    else if (mat == 1) Btv[o] = h;
    else {
      unsigned short* Bh = (mat == 2) ? Btqh : (mat == 3) ? Btoffh : Btoh;
      unsigned short* Bl = (mat == 2) ? Btql : (mat == 3) ? Btoffl : Btol;
      Bh[o] = h;
      Bl[o] = f2bf(v - bf2f(h));
    }
  }
}

// ---------------------------------------------------------------------------
// hi/lo-split bf16 MFMA GEMM (~f32 accuracy): C = A @ Bt^T + bias, f32 out.
// ---------------------------------------------------------------------------
__global__ __launch_bounds__(256) void gemm_hl_mfma(
    const float* __restrict__ A,
    const unsigned short* __restrict__ Bth,
    const unsigned short* __restrict__ Btl,
    const float* __restrict__ bias, float* __restrict__ C, int M) {
  const int P = 40;
  __shared__ short Ah[64 * P], Al[64 * P], Bh[64 * P], Bl[64 * P];
  int tid = threadIdx.x;
  int m0 = blockIdx.x * 64, n0 = blockIdx.y * 64;
  int w = tid >> 6, l = tid & 63;
  int r = l & 15, g = l >> 4;
  int mi = (w >> 1) * 32, ni = (w & 1) * 32;
  int sm = tid >> 2, sp = tid & 3;

  f32x4 acc[2][2];
  #pragma unroll
  for (int a = 0; a < 2; a++)
    #pragma unroll
    for (int b = 0; b < 2; b++) acc[a][b] = (f32x4){0.f, 0.f, 0.f, 0.f};

  for (int k0 = 0; k0 < 256; k0 += 32) {
    int gm = m0 + sm;
    float f[8];
    if (gm < M) {
      const float* src = A + (size_t)gm * 256 + k0 + sp * 8;
      float4 u0 = *(const float4*)src;
      float4 u1 = *(const float4*)(src + 4);
      f[0] = u0.x; f[1] = u0.y; f[2] = u0.z; f[3] = u0.w;
      f[4] = u1.x; f[5] = u1.y; f[6] = u1.z; f[7] = u1.w;
    } else {
      #pragma unroll
      for (int j = 0; j < 8; j++) f[j] = 0.f;
    }
    short8v hv, lv;
    #pragma unroll
    for (int j = 0; j < 8; j++) {
      unsigned short h = f2bf(f[j]);
      hv[j] = (short)h;
      lv[j] = (short)f2bf(f[j] - bf2f(h));
    }
    *(short8v*)&Ah[sm * P + sp * 8] = hv;
    *(short8v*)&Al[sm * P + sp * 8] = lv;
    *(short8v*)&Bh[sm * P + sp * 8] =
        *(const short8v*)&Bth[(size_t)(n0 + sm) * 256 + k0 + sp * 8];
    *(short8v*)&Bl[sm * P + sp * 8] =
        *(const short8v*)&Btl[(size_t)(n0 + sm) * 256 + k0 + sp * 8];
    __syncthreads();

    short8v ah[2], al[2], bh[2], bl[2];
    #pragma unroll
    for (int a = 0; a < 2; a++) {
      ah[a] = *(short8v*)&Ah[(mi + a * 16 + r) * P + g * 8];
      al[a] = *(short8v*)&Al[(mi + a * 16 + r) * P + g * 8];
    }
    #pragma unroll
    for (int b = 0; b < 2; b++) {
      bh[b] = *(short8v*)&Bh[(ni + b * 16 + r) * P + g * 8];
      bl[b] = *(short8v*)&Bl[(ni + b * 16 + r) * P + g * 8];
    }
    #pragma unroll
    for (int a = 0; a < 2; a++)
      #pragma unroll
      for (int b = 0; b < 2; b++) {
        acc[a][b] = __builtin_amdgcn_mfma_f32_16x16x32_bf16(ah[a], bh[b], acc[a][b], 0, 0, 0);
        acc[a][b] = __builtin_amdgcn_mfma_f32_16x16x32_bf16(al[a], bh[b], acc[a][b], 0, 0, 0);
        acc[a][b] = __builtin_amdgcn_mfma_f32_16x16x32_bf16(ah[a], bl[b], acc[a][b], 0, 0, 0);
      }
    __syncthreads();
  }

  #pragma unroll
  for (int a = 0; a < 2; a++)
    #pragma unroll
    for (int b = 0; b < 2; b++) {
      int col = n0 + ni + b * 16 + r;
      float bc = bias[col];
      #pragma unroll
      for (int i = 0; i < 4; i++) {
        int row = m0 + mi + a * 16 + g * 4 + i;
        if (row < M) C[(size_t)row * 256 + col] = acc[a][b][i] + bc;
      }
    }
}

// ---------------------------------------------------------------------------
// Fused K+V projection, bf16 MFMA, hi/lo on A; packed **f16** {k|v<<16} out.
// ---------------------------------------------------------------------------
__global__ __launch_bounds__(256) void gemm_kv_mfma(
    const float* __restrict__ A,
    const unsigned short* __restrict__ Btk,
    const unsigned short* __restrict__ Btv,
    const float* __restrict__ bk, const float* __restrict__ bv,
    unsigned* __restrict__ kvout, int M) {
  const int P = 40;
  __shared__ short Ah[64 * P], Al[64 * P], Bk[64 * P], Bv[64 * P];
  int tid = threadIdx.x;
  int m0 = blockIdx.x * 64, n0 = blockIdx.y * 64;
  int w = tid >> 6, l = tid & 63;
  int r = l & 15, g = l >> 4;
  int mi = (w >> 1) * 32, ni = (w & 1) * 32;
  int sm = tid >> 2, sp = tid & 3;

  f32x4 acck[2][2], accv[2][2];
  #pragma unroll
  for (int a = 0; a < 2; a++)
    #pragma unroll
    for (int b = 0; b < 2; b++) {
      acck[a][b] = (f32x4){0.f, 0.f, 0.f, 0.f};
      accv[a][b] = (f32x4){0.f, 0.f, 0.f, 0.f};
    }

  for (int k0 = 0; k0 < 256; k0 += 32) {
    int gm = m0 + sm;
    float f[8];
    if (gm < M) {
      const float* src = A + (size_t)gm * 256 + k0 + sp * 8;
      float4 u0 = *(const float4*)src;
      float4 u1 = *(const float4*)(src + 4);
      f[0] = u0.x; f[1] = u0.y; f[2] = u0.z; f[3] = u0.w;
      f[4] = u1.x; f[5] = u1.y; f[6] = u1.z; f[7] = u1.w;
    } else {
      #pragma unroll
      for (int j = 0; j < 8; j++) f[j] = 0.f;
    }
    short8v hv, lv;
    #pragma unroll
    for (int j = 0; j < 8; j++) {
      unsigned short h = f2bf(f[j]);
      hv[j] = (short)h;
      lv[j] = (short)f2bf(f[j] - bf2f(h));
    }
    *(short8v*)&Ah[sm * P + sp * 8] = hv;
    *(short8v*)&Al[sm * P + sp * 8] = lv;
    *(short8v*)&Bk[sm * P + sp * 8] =
        *(const short8v*)&Btk[(size_t)(n0 + sm) * 256 + k0 + sp * 8];
    *(short8v*)&Bv[sm * P + sp * 8] =
        *(const short8v*)&Btv[(size_t)(n0 + sm) * 256 + k0 + sp * 8];
    __syncthreads();

    short8v ah[2], al[2], fbk[2], fbv[2];
    #pragma unroll
    for (int a = 0; a < 2; a++) {
      ah[a] = *(short8v*)&Ah[(mi + a * 16 + r) * P + g * 8];
      al[a] = *(short8v*)&Al[(mi + a * 16 + r) * P + g * 8];
    }
    #pragma unroll
    for (int b = 0; b < 2; b++) {
      fbk[b] = *(short8v*)&Bk[(ni + b * 16 + r) * P + g * 8];
      fbv[b] = *(short8v*)&Bv[(ni + b * 16 + r) * P + g * 8];
    }
    #pragma unroll
    for (int a = 0; a < 2; a++)
      #pragma unroll
      for (int b = 0; b < 2; b++) {
        acck[a][b] = __builtin_amdgcn_mfma_f32_16x16x32_bf16(ah[a], fbk[b], acck[a][b], 0, 0, 0);
        acck[a][b] = __builtin_amdgcn_mfma_f32_16x16x32_bf16(al[a], fbk[b], acck[a][b], 0, 0, 0);
        accv[a][b] = __builtin_amdgcn_mfma_f32_16x16x32_bf16(ah[a], fbv[b], accv[a][b], 0, 0, 0);
        accv[a][b] = __builtin_amdgcn_mfma_f32_16x16x32_bf16(al[a], fbv[b], accv[a][b], 0, 0, 0);
      }
    __syncthreads();
  }

  #pragma unroll
  for (int a = 0; a < 2; a++)
    #pragma unroll
    for (int b = 0; b < 2; b++) {
      int col = n0 + ni + b * 16 + r;
      float bkc = bk[col], bvc = bv[col];
      #pragma unroll
      for (int i = 0; i < 4; i++) {
        int row = m0 + mi + a * 16 + g * 4 + i;
        if (row < M) {
          unsigned kh = f2h16(acck[a][b][i] + bkc);
          unsigned vh = f2h16(accv[a][b][i] + bvc);
          kvout[(size_t)row * 256 + col] = kh | (vh << 16);
        }
      }
    }
}

// ---------------------------------------------------------------------------
// Sampling + attention v3b: one wave per (query, head).
// Lane = (point lane>>2, 8-channel chunk (lane&3)*8). Single 16-point pass.
// All 8 tap loads issued before accumulation (MLP); packed f16 FMA.
// ---------------------------------------------------------------------------
__global__ __launch_bounds__(256) void sample_attn(
    const float* __restrict__ qp,
    const float* __restrict__ offs,
    const float* __restrict__ rp,
    const unsigned* __restrict__ kv,   // packed f16 {k | v<<16}
    float* __restrict__ attn_out) {
  __shared__ float lbuf[4][16];
  __shared__ float ebuf[4][16];
  __shared__ float vbuf[4][16][36];   // +4 pad: 16-way -> 2-way bank alias

  int tid = threadIdx.x;
  int wslot = tid >> 6;
  int lane = tid & 63;
  int wid = blockIdx.x * 4 + wslot;
  int q = wid >> 3;
  int h = wid & 7;

  int pt = lane >> 2;        // point 0..15
  int c8 = (lane & 3) * 8;   // channel chunk base
  int l5 = lane & 31;

  float offv = offs[(size_t)q * D_MODEL + h * 32 + l5];
  float rpv = (l5 < 8) ? rp[(size_t)q * 8 + l5] : 0.f;

  int l = pt >> 2, pp = pt & 3;
  int W = 112 >> l;
  int start = (int)((50176u - (50176u >> (2 * l))) / 3u);  // 0,12544,15680,16464

  float off_x = __shfl(offv, l * 8 + pp * 2 + 0, 64);
  float off_y = __shfl(offv, l * 8 + pp * 2 + 1, 64);
  float rp_x = __shfl(rpv, l * 2 + 0, 64);
  float rp_y = __shfl(rpv, l * 2 + 1, 64);

  float x = rp_x * (float)W + off_x - 0.5f;
  float y = rp_y * (float)W + off_y - 0.5f;
  float x0f = floorf(x), y0f = floorf(y);
  float lx = x - x0f, ly = y - y0f;
  int x0 = (int)x0f, y0 = (int)y0f;
  float wx0 = 1.f - lx, wy0 = 1.f - ly;
  float tw[4] = {wy0 * wx0, wy0 * lx, ly * wx0, ly * lx};

  int hoff = h * 32 + c8;

  // compute all tap addresses + weights, then issue all 8 loads (MLP)
  float wgt[4];
  const unsigned* addr[4];
  #pragma unroll
  for (int tap = 0; tap < 4; tap++) {
    int yy = y0 + (tap >> 1), xx = x0 + (tap & 1);
    bool valid = ((unsigned)xx < (unsigned)W) & ((unsigned)yy < (unsigned)W);
    wgt[tap] = valid ? tw[tap] : 0.f;
    int pix = valid ? (start + yy * W + xx) : start;
    addr[tap] = kv + (size_t)pix * D_MODEL + hoff;
  }
  uint4 ld0[4], ld1[4];
  #pragma unroll
  for (int tap = 0; tap < 4; tap++) {
    ld0[tap] = *(const uint4*)addr[tap];
    ld1[tap] = *(const uint4*)(addr[tap] + 4);
  }

  f16x2 acc[8];
  #pragma unroll
  for (int j = 0; j < 8; j++) acc[j] = (f16x2){(_Float16)0.f, (_Float16)0.f};
  #pragma unroll
  for (int tap = 0; tap < 4; tap++) {
    _Float16 wh = (_Float16)wgt[tap];
    f16x2 w2 = {wh, wh};
    acc[0] += w2 * u2h(ld0[tap].x);
    acc[1] += w2 * u2h(ld0[tap].y);
    acc[2] += w2 * u2h(ld0[tap].z);
    acc[3] += w2 * u2h(ld0[tap].w);
    acc[4] += w2 * u2h(ld1[tap].x);
    acc[5] += w2 * u2h(ld1[tap].y);
    acc[6] += w2 * u2h(ld1[tap].z);
    acc[7] += w2 * u2h(ld1[tap].w);
  }

  // q . k over this lane's 8 channels (k = low half of acc pairs)
  const float* qsrc = qp + (size_t)q * D_MODEL + hoff;
  float4 qa = *(const float4*)qsrc;
  float4 qb = *(const float4*)(qsrc + 4);
  float dot = qa.x * (float)acc[0][0] + qa.y * (float)acc[1][0]
            + qa.z * (float)acc[2][0] + qa.w * (float)acc[3][0]
            + qb.x * (float)acc[4][0] + qb.y * (float)acc[5][0]
            + qb.z * (float)acc[6][0] + qb.w * (float)acc[7][0];
  dot += __shfl_xor(dot, 1, 64);
  dot += __shfl_xor(dot, 2, 64);
  if ((lane & 3) == 0) lbuf[wslot][pt] = dot * 0.17677669529663687f;

  // v (high halves) to f32, into LDS
  float4 v0 = {(float)acc[0][1], (float)acc[1][1], (float)acc[2][1], (float)acc[3][1]};
  float4 v1 = {(float)acc[4][1], (float)acc[5][1], (float)acc[6][1], (float)acc[7][1]};
  *(float4*)&vbuf[wslot][pt][c8] = v0;
  *(float4*)&vbuf[wslot][pt][c8 + 4] = v1;
  __syncthreads();

  // softmax over 16 points (redundant per 16-lane group, 1 exp per lane)
  float lg = lbuf[wslot][lane & 15];
  float m = lg;
  m = fmaxf(m, __shfl_xor(m, 1, 64));
  m = fmaxf(m, __shfl_xor(m, 2, 64));
  m = fmaxf(m, __shfl_xor(m, 4, 64));
  m = fmaxf(m, __shfl_xor(m, 8, 64));
  float e = __expf(lg - m);
  float s = e;
  s += __shfl_xor(s, 1, 64);
  s += __shfl_xor(s, 2, 64);
  s += __shfl_xor(s, 4, 64);
  s += __shfl_xor(s, 8, 64);
  if (lane < 16) ebuf[wslot][lane] = e;
  float inv = 1.f / s;
  __syncthreads();

  if (lane < 32) {
    float o = 0.f;
    #pragma unroll
    for (int p = 0; p < 16; p++) o += ebuf[wslot][p] * vbuf[wslot][p][lane];
    attn_out[(size_t)q * D_MODEL + h * 32 + lane] = o * inv;
  }
}

extern "C" void kernel_launch(void* const* d_in, const int* in_sizes, int n_in,
                              void* d_out, int out_size, void* d_ws, size_t ws_size,
                              hipStream_t stream) {
  const float* query = (const float*)d_in[0];
  const float* rp    = (const float*)d_in[1];
  const float* inp   = (const float*)d_in[2];
  const float* W_q   = (const float*)d_in[5];
  const float* b_q   = (const float*)d_in[6];
  const float* W_k   = (const float*)d_in[7];
  const float* b_k   = (const float*)d_in[8];
  const float* W_v   = (const float*)d_in[9];
  const float* b_v   = (const float*)d_in[10];
  const float* W_o   = (const float*)d_in[11];
  const float* b_o   = (const float*)d_in[12];
  const float* W_off = (const float*)d_in[13];
  const float* b_off = (const float*)d_in[14];
  float* out = (float*)d_out;

  const size_t nelem = (size_t)LEN_IN * D_MODEL;  // 4,264,960
  float* qp   = (float*)d_ws;
  float* offs = qp + nelem;
  float* attn = offs + nelem;
  unsigned* kvp = (unsigned*)(attn + nelem);
  unsigned short* Btk    = (unsigned short*)(kvp + nelem);
  unsigned short* Btv    = Btk + 256 * 256;
  unsigned short* Btqh   = Btv + 256 * 256;
  unsigned short* Btql   = Btqh + 256 * 256;
  unsigned short* Btoffh = Btql + 256 * 256;
  unsigned short* Btoffl = Btoffh + 256 * 256;
  unsigned short* Btoh   = Btoffl + 256 * 256;
  unsigned short* Btol   = Btoh + 256 * 256;

  dim3 blk(256);
  dim3 ggrid((LEN_IN + 63) / 64, D_MODEL / 64);  // (261, 4)

  prep_B<<<80, blk, 0, stream>>>(W_k, W_v, W_q, W_off, W_o,
                                 Btk, Btv, Btqh, Btql, Btoffh, Btoffl, Btoh, Btol);
  gemm_hl_mfma<<<ggrid, blk, 0, stream>>>(query, Btqh, Btql, b_q, qp, LEN_IN);
  gemm_kv_mfma<<<ggrid, blk, 0, stream>>>(inp, Btk, Btv, b_k, b_v, kvp, LEN_IN);
  gemm_hl_mfma<<<ggrid, blk, 0, stream>>>(qp, Btoffh, Btoffl, b_off, offs, LEN_IN);

  int n_blocks = LEN_IN * N_HEADS / 4;  // 33320
  sample_attn<<<n_blocks, blk, 0, stream>>>(qp, offs, rp, kvp, attn);

  gemm_hl_mfma<<<ggrid, blk, 0, stream>>>(attn, Btoh, Btol, b_o, out, LEN_IN);
}

// Round 9
// 130.144 us; speedup vs baseline: 1.2908x; 1.1339x over previous
//
#include <hip/hip_runtime.h>
#include <hip/hip_bf16.h>
#include <math.h>

#define LEN_IN   16660
#define D_MODEL  256
#define N_HEADS  8
#define HEAD_DIM 32
#define N_LEVELS 4
#define N_POINTS 4

typedef __attribute__((ext_vector_type(8))) short short8v;
typedef __attribute__((ext_vector_type(4))) float f32x4;
typedef _Float16 f16x2 __attribute__((ext_vector_type(2)));
typedef _Float16 f16x8 __attribute__((ext_vector_type(8)));

__device__ __forceinline__ unsigned f2h16(float f) {  // f32 -> f16 bits (RN)
  _Float16 h = (_Float16)f;
  union { unsigned short u; _Float16 h; } c;
  c.h = h;
  return (unsigned)c.u;
}
__device__ __forceinline__ f16x2 u2h(unsigned u) {
  union { unsigned u; f16x2 h; } c;
  c.u = u;
  return c.h;
}

// ---------------------------------------------------------------------------
// Prep: transpose + f16-cast 5 weight matrices. Bt[n][k] = f16(W[k][n]).
// 5 matrices x 16 tiles = 80 blocks.
// ---------------------------------------------------------------------------
__global__ __launch_bounds__(256) void prep_B(
    const float* __restrict__ Wq, const float* __restrict__ Wk,
    const float* __restrict__ Wv, const float* __restrict__ Woff,
    const float* __restrict__ Wo,
    unsigned short* __restrict__ Btq, unsigned short* __restrict__ Btk,
    unsigned short* __restrict__ Btv, unsigned short* __restrict__ Btoff,
    unsigned short* __restrict__ Bto) {
  __shared__ float tile[64][65];
  int b = blockIdx.x;
  int mat = b >> 4, t = b & 15;
  int ti = t >> 2, tj = t & 3;  // ti: k-tile, tj: n-tile
  const float* W = (mat == 0) ? Wq : (mat == 1) ? Wk : (mat == 2) ? Wv
                 : (mat == 3) ? Woff : Wo;
  unsigned short* Bt = (mat == 0) ? Btq : (mat == 1) ? Btk : (mat == 2) ? Btv
                     : (mat == 3) ? Btoff : Bto;
  int tid = threadIdx.x;
  #pragma unroll
  for (int i = 0; i < 16; i++) {
    int idx = tid + i * 256;
    int kr = idx >> 6, nc = idx & 63;
    tile[kr][nc] = W[(size_t)(ti * 64 + kr) * 256 + tj * 64 + nc];
  }
  __syncthreads();
  #pragma unroll
  for (int i = 0; i < 16; i++) {
    int idx = tid + i * 256;
    int nr = idx >> 6, kc = idx & 63;
    Bt[(size_t)(tj * 64 + nr) * 256 + ti * 64 + kc] =
        (unsigned short)f2h16(tile[kc][nr]);
  }
}

// ---------------------------------------------------------------------------
// Single-pass f16 MFMA GEMM: C = A @ Bt^T + bias, f32 out.
// rel err ~2.4e-4 (f16 input rounding only; f32 accumulate).
// Tile 64x64, 4 waves (2x2), each wave 32x32 = 2x2 frags of 16x16x32.
// ---------------------------------------------------------------------------
__global__ __launch_bounds__(256) void gemm_f16(
    const float* __restrict__ A,
    const unsigned short* __restrict__ Bt,  // f16 bits, [n][k]
    const float* __restrict__ bias, float* __restrict__ C, int M) {
  const int P = 40;  // LDS pitch in shorts
  __shared__ short As[64 * P], Bs[64 * P];
  int tid = threadIdx.x;
  int m0 = blockIdx.x * 64, n0 = blockIdx.y * 64;
  int w = tid >> 6, l = tid & 63;
  int r = l & 15, g = l >> 4;
  int mi = (w >> 1) * 32, ni = (w & 1) * 32;
  int sm = tid >> 2, sp = tid & 3;

  f32x4 acc[2][2];
  #pragma unroll
  for (int a = 0; a < 2; a++)
    #pragma unroll
    for (int b = 0; b < 2; b++) acc[a][b] = (f32x4){0.f, 0.f, 0.f, 0.f};

  for (int k0 = 0; k0 < 256; k0 += 32) {
    int gm = m0 + sm;
    float f[8];
    if (gm < M) {
      const float* src = A + (size_t)gm * 256 + k0 + sp * 8;
      float4 u0 = *(const float4*)src;
      float4 u1 = *(const float4*)(src + 4);
      f[0] = u0.x; f[1] = u0.y; f[2] = u0.z; f[3] = u0.w;
      f[4] = u1.x; f[5] = u1.y; f[6] = u1.z; f[7] = u1.w;
    } else {
      #pragma unroll
      for (int j = 0; j < 8; j++) f[j] = 0.f;
    }
    f16x8 hv;
    #pragma unroll
    for (int j = 0; j < 8; j++) hv[j] = (_Float16)f[j];
    *(f16x8*)&As[sm * P + sp * 8] = hv;
    *(short8v*)&Bs[sm * P + sp * 8] =
        *(const short8v*)&Bt[(size_t)(n0 + sm) * 256 + k0 + sp * 8];
    __syncthreads();

    f16x8 af[2], bf[2];
    #pragma unroll
    for (int a = 0; a < 2; a++)
      af[a] = *(f16x8*)&As[(mi + a * 16 + r) * P + g * 8];
    #pragma unroll
    for (int b = 0; b < 2; b++)
      bf[b] = *(f16x8*)&Bs[(ni + b * 16 + r) * P + g * 8];
    #pragma unroll
    for (int a = 0; a < 2; a++)
      #pragma unroll
      for (int b = 0; b < 2; b++)
        acc[a][b] = __builtin_amdgcn_mfma_f32_16x16x32_f16(af[a], bf[b], acc[a][b], 0, 0, 0);
    __syncthreads();
  }

  #pragma unroll
  for (int a = 0; a < 2; a++)
    #pragma unroll
    for (int b = 0; b < 2; b++) {
      int col = n0 + ni + b * 16 + r;
      float bc = bias[col];
      #pragma unroll
      for (int i = 0; i < 4; i++) {
        int row = m0 + mi + a * 16 + g * 4 + i;
        if (row < M) C[(size_t)row * 256 + col] = acc[a][b][i] + bc;
      }
    }
}

// ---------------------------------------------------------------------------
// Fused K+V projection, single-pass f16 MFMA; packed f16 {k|v<<16} out.
// ---------------------------------------------------------------------------
__global__ __launch_bounds__(256) void gemm_kv_f16(
    const float* __restrict__ A,
    const unsigned short* __restrict__ Btk,
    const unsigned short* __restrict__ Btv,
    const float* __restrict__ bk, const float* __restrict__ bv,
    unsigned* __restrict__ kvout, int M) {
  const int P = 40;
  __shared__ short As[64 * P], Bks[64 * P], Bvs[64 * P];
  int tid = threadIdx.x;
  int m0 = blockIdx.x * 64, n0 = blockIdx.y * 64;
  int w = tid >> 6, l = tid & 63;
  int r = l & 15, g = l >> 4;
  int mi = (w >> 1) * 32, ni = (w & 1) * 32;
  int sm = tid >> 2, sp = tid & 3;

  f32x4 acck[2][2], accv[2][2];
  #pragma unroll
  for (int a = 0; a < 2; a++)
    #pragma unroll
    for (int b = 0; b < 2; b++) {
      acck[a][b] = (f32x4){0.f, 0.f, 0.f, 0.f};
      accv[a][b] = (f32x4){0.f, 0.f, 0.f, 0.f};
    }

  for (int k0 = 0; k0 < 256; k0 += 32) {
    int gm = m0 + sm;
    float f[8];
    if (gm < M) {
      const float* src = A + (size_t)gm * 256 + k0 + sp * 8;
      float4 u0 = *(const float4*)src;
      float4 u1 = *(const float4*)(src + 4);
      f[0] = u0.x; f[1] = u0.y; f[2] = u0.z; f[3] = u0.w;
      f[4] = u1.x; f[5] = u1.y; f[6] = u1.z; f[7] = u1.w;
    } else {
      #pragma unroll
      for (int j = 0; j < 8; j++) f[j] = 0.f;
    }
    f16x8 hv;
    #pragma unroll
    for (int j = 0; j < 8; j++) hv[j] = (_Float16)f[j];
    *(f16x8*)&As[sm * P + sp * 8] = hv;
    *(short8v*)&Bks[sm * P + sp * 8] =
        *(const short8v*)&Btk[(size_t)(n0 + sm) * 256 + k0 + sp * 8];
    *(short8v*)&Bvs[sm * P + sp * 8] =
        *(const short8v*)&Btv[(size_t)(n0 + sm) * 256 + k0 + sp * 8];
    __syncthreads();

    f16x8 af[2], fbk[2], fbv[2];
    #pragma unroll
    for (int a = 0; a < 2; a++)
      af[a] = *(f16x8*)&As[(mi + a * 16 + r) * P + g * 8];
    #pragma unroll
    for (int b = 0; b < 2; b++) {
      fbk[b] = *(f16x8*)&Bks[(ni + b * 16 + r) * P + g * 8];
      fbv[b] = *(f16x8*)&Bvs[(ni + b * 16 + r) * P + g * 8];
    }
    #pragma unroll
    for (int a = 0; a < 2; a++)
      #pragma unroll
      for (int b = 0; b < 2; b++) {
        acck[a][b] = __builtin_amdgcn_mfma_f32_16x16x32_f16(af[a], fbk[b], acck[a][b], 0, 0, 0);
        accv[a][b] = __builtin_amdgcn_mfma_f32_16x16x32_f16(af[a], fbv[b], accv[a][b], 0, 0, 0);
      }
    __syncthreads();
  }

  #pragma unroll
  for (int a = 0; a < 2; a++)
    #pragma unroll
    for (int b = 0; b < 2; b++) {
      int col = n0 + ni + b * 16 + r;
      float bkc = bk[col], bvc = bv[col];
      #pragma unroll
      for (int i = 0; i < 4; i++) {
        int row = m0 + mi + a * 16 + g * 4 + i;
        if (row < M) {
          unsigned kh = f2h16(acck[a][b][i] + bkc);
          unsigned vh = f2h16(accv[a][b][i] + bvc);
          kvout[(size_t)row * 256 + col] = kh | (vh << 16);
        }
      }
    }
}

// ---------------------------------------------------------------------------
// Sampling + attention (R7-proven): one wave per (query, head).
// Lane = (point lane>>2, 8-channel chunk (lane&3)*8). Single 16-point pass.
// Taps weighted with packed f16 FMA on the {k,v} pair — no unpacking.
// ---------------------------------------------------------------------------
__global__ __launch_bounds__(256) void sample_attn(
    const float* __restrict__ qp,
    const float* __restrict__ offs,
    const float* __restrict__ rp,
    const unsigned* __restrict__ kv,   // packed f16 {k | v<<16}
    float* __restrict__ attn_out) {
  __shared__ float lbuf[4][16];
  __shared__ float ebuf[4][16];
  __shared__ float vbuf[4][16][36];   // +4 pad: 16-way -> 2-way bank alias

  int tid = threadIdx.x;
  int wslot = tid >> 6;
  int lane = tid & 63;
  int wid = blockIdx.x * 4 + wslot;
  int q = wid >> 3;
  int h = wid & 7;

  int pt = lane >> 2;        // point 0..15
  int c8 = (lane & 3) * 8;   // channel chunk base
  int l5 = lane & 31;

  float offv = offs[(size_t)q * D_MODEL + h * 32 + l5];
  float rpv = (l5 < 8) ? rp[(size_t)q * 8 + l5] : 0.f;

  int l = pt >> 2, pp = pt & 3;
  int W = 112 >> l;
  int start = (int)((50176u - (50176u >> (2 * l))) / 3u);  // 0,12544,15680,16464

  float off_x = __shfl(offv, l * 8 + pp * 2 + 0, 64);
  float off_y = __shfl(offv, l * 8 + pp * 2 + 1, 64);
  float rp_x = __shfl(rpv, l * 2 + 0, 64);
  float rp_y = __shfl(rpv, l * 2 + 1, 64);

  float x = rp_x * (float)W + off_x - 0.5f;
  float y = rp_y * (float)W + off_y - 0.5f;
  float x0f = floorf(x), y0f = floorf(y);
  float lx = x - x0f, ly = y - y0f;
  int x0 = (int)x0f, y0 = (int)y0f;
  float wx0 = 1.f - lx, wy0 = 1.f - ly;
  float tw[4] = {wy0 * wx0, wy0 * lx, ly * wx0, ly * lx};

  int hoff = h * 32 + c8;

  f16x2 acc[8];
  #pragma unroll
  for (int j = 0; j < 8; j++) acc[j] = (f16x2){(_Float16)0.f, (_Float16)0.f};

  #pragma unroll
  for (int tap = 0; tap < 4; tap++) {
    int yy = y0 + (tap >> 1), xx = x0 + (tap & 1);
    bool valid = ((unsigned)xx < (unsigned)W) & ((unsigned)yy < (unsigned)W);
    float wgt = valid ? tw[tap] : 0.f;
    int pix = valid ? (start + yy * W + xx) : start;
    const unsigned* p = kv + (size_t)pix * D_MODEL + hoff;
    uint4 u0 = *(const uint4*)p;
    uint4 u1 = *(const uint4*)(p + 4);
    _Float16 wh = (_Float16)wgt;
    f16x2 w2 = {wh, wh};
    acc[0] += w2 * u2h(u0.x);
    acc[1] += w2 * u2h(u0.y);
    acc[2] += w2 * u2h(u0.z);
    acc[3] += w2 * u2h(u0.w);
    acc[4] += w2 * u2h(u1.x);
    acc[5] += w2 * u2h(u1.y);
    acc[6] += w2 * u2h(u1.z);
    acc[7] += w2 * u2h(u1.w);
  }

  // q . k over this lane's 8 channels (k = low half of acc pairs)
  const float* qsrc = qp + (size_t)q * D_MODEL + hoff;
  float4 qa = *(const float4*)qsrc;
  float4 qb = *(const float4*)(qsrc + 4);
  float dot = qa.x * (float)acc[0][0] + qa.y * (float)acc[1][0]
            + qa.z * (float)acc[2][0] + qa.w * (float)acc[3][0]
            + qb.x * (float)acc[4][0] + qb.y * (float)acc[5][0]
            + qb.z * (float)acc[6][0] + qb.w * (float)acc[7][0];
  dot += __shfl_xor(dot, 1, 64);
  dot += __shfl_xor(dot, 2, 64);
  if ((lane & 3) == 0) lbuf[wslot][pt] = dot * 0.17677669529663687f;

  // v (high halves) to f32, into LDS
  float4 v0 = {(float)acc[0][1], (float)acc[1][1], (float)acc[2][1], (float)acc[3][1]};
  float4 v1 = {(float)acc[4][1], (float)acc[5][1], (float)acc[6][1], (float)acc[7][1]};
  *(float4*)&vbuf[wslot][pt][c8] = v0;
  *(float4*)&vbuf[wslot][pt][c8 + 4] = v1;
  __syncthreads();

  // softmax over 16 points (redundant per 16-lane group, 1 exp per lane)
  float lg = lbuf[wslot][lane & 15];
  float m = lg;
  m = fmaxf(m, __shfl_xor(m, 1, 64));
  m = fmaxf(m, __shfl_xor(m, 2, 64));
  m = fmaxf(m, __shfl_xor(m, 4, 64));
  m = fmaxf(m, __shfl_xor(m, 8, 64));
  float e = __expf(lg - m);
  float s = e;
  s += __shfl_xor(s, 1, 64);
  s += __shfl_xor(s, 2, 64);
  s += __shfl_xor(s, 4, 64);
  s += __shfl_xor(s, 8, 64);
  if (lane < 16) ebuf[wslot][lane] = e;
  float inv = 1.f / s;
  __syncthreads();

  if (lane < 32) {
    float o = 0.f;
    #pragma unroll
    for (int p = 0; p < 16; p++) o += ebuf[wslot][p] * vbuf[wslot][p][lane];
    attn_out[(size_t)q * D_MODEL + h * 32 + lane] = o * inv;
  }
}

extern "C" void kernel_launch(void* const* d_in, const int* in_sizes, int n_in,
                              void* d_out, int out_size, void* d_ws, size_t ws_size,
                              hipStream_t stream) {
  const float* query = (const float*)d_in[0];
  const float* rp    = (const float*)d_in[1];
  const float* inp   = (const float*)d_in[2];
  const float* W_q   = (const float*)d_in[5];
  const float* b_q   = (const float*)d_in[6];
  const float* W_k   = (const float*)d_in[7];
  const float* b_k   = (const float*)d_in[8];
  const float* W_v   = (const float*)d_in[9];
  const float* b_v   = (const float*)d_in[10];
  const float* W_o   = (const float*)d_in[11];
  const float* b_o   = (const float*)d_in[12];
  const float* W_off = (const float*)d_in[13];
  const float* b_off = (const float*)d_in[14];
  float* out = (float*)d_out;

  const size_t nelem = (size_t)LEN_IN * D_MODEL;  // 4,264,960
  float* qp   = (float*)d_ws;
  float* offs = qp + nelem;
  float* attn = offs + nelem;
  unsigned* kvp = (unsigned*)(attn + nelem);
  unsigned short* Btq   = (unsigned short*)(kvp + nelem);
  unsigned short* Btk   = Btq + 256 * 256;
  unsigned short* Btv   = Btk + 256 * 256;
  unsigned short* Btoff = Btv + 256 * 256;
  unsigned short* Bto   = Btoff + 256 * 256;

  dim3 blk(256);
  dim3 ggrid((LEN_IN + 63) / 64, D_MODEL / 64);  // (261, 4)

  prep_B<<<80, blk, 0, stream>>>(W_q, W_k, W_v, W_off, W_o,
                                 Btq, Btk, Btv, Btoff, Bto);
  gemm_f16<<<ggrid, blk, 0, stream>>>(query, Btq, b_q, qp, LEN_IN);
  gemm_kv_f16<<<ggrid, blk, 0, stream>>>(inp, Btk, Btv, b_k, b_v, kvp, LEN_IN);
  gemm_f16<<<ggrid, blk, 0, stream>>>(qp, Btoff, b_off, offs, LEN_IN);

  int n_blocks = LEN_IN * N_HEADS / 4;  // 33320
  sample_attn<<<n_blocks, blk, 0, stream>>>(qp, offs, rp, kvp, attn);

  gemm_f16<<<ggrid, blk, 0, stream>>>(attn, Bto, b_o, out, LEN_IN);
}